// Round 5
// baseline (268.843 us; speedup 1.0000x reference)
//
#include <hip/hip_runtime.h>

#define B_   8
#define T_   4096
#define D_   1024
#define E_   100
#define EP_  128
#define NTOK (B_*T_)
#define TC_  8            // t-chunks in k_feat
#define KT_  (T_/TC_)     // 512

typedef short bf16x8 __attribute__((ext_vector_type(8)));
typedef float f32x4  __attribute__((ext_vector_type(4)));

__device__ __forceinline__ unsigned short f2b(float f){
    union { float f; unsigned int i; } v; v.f = f;
    unsigned int x = v.i;
    return (unsigned short)((x + 0x7fffu + ((x >> 16) & 1u)) >> 16);
}
__device__ __forceinline__ uint4 pack8(float4 a, float4 b){
    uint4 r;
    r.x = (unsigned int)f2b(a.x) | ((unsigned int)f2b(a.y) << 16);
    r.y = (unsigned int)f2b(a.z) | ((unsigned int)f2b(a.w) << 16);
    r.z = (unsigned int)f2b(b.x) | ((unsigned int)f2b(b.y) << 16);
    r.w = (unsigned int)f2b(b.z) | ((unsigned int)f2b(b.w) << 16);
    return r;
}
__device__ __forceinline__ bf16x8 pk(float4 a, float4 b){
    union { uint4 u; bf16x8 h; } c; c.u = pack8(a, b); return c.h;
}
__device__ __forceinline__ void dma16(const unsigned short* g, unsigned short* l){
    __builtin_amdgcn_global_load_lds(
        (const __attribute__((address_space(1))) unsigned int*)(const void*)g,
        (__attribute__((address_space(3))) unsigned int*)(void*)l,
        16, 0, 0);
}

// ---------------- K1: normalize centroids (fp32 in) -> cn[EP_][D_] bf16 --------
__global__ __launch_bounds__(256) void k_cnorm(const float* __restrict__ cent,
                                               unsigned short* __restrict__ cn){
    const int e = blockIdx.x, tid = threadIdx.x;
    if (e >= E_){
        ((uint2*)(cn + (size_t)e*D_))[tid] = make_uint2(0u, 0u);
        return;
    }
    float4 x = ((const float4*)(cent + (size_t)e*D_))[tid];
    float ss = x.x*x.x + x.y*x.y + x.z*x.z + x.w*x.w;
    __shared__ float red[256];
    red[tid] = ss; __syncthreads();
    for (int s = 128; s > 0; s >>= 1){ if (tid < s) red[tid] += red[tid+s]; __syncthreads(); }
    float inv = 1.0f / fmaxf(sqrtf(red[0]), 1e-12f);
    unsigned int lo = (unsigned int)f2b(x.x*inv) | ((unsigned int)f2b(x.y*inv) << 16);
    unsigned int hi = (unsigned int)f2b(x.z*inv) | ((unsigned int)f2b(x.w*inv) << 16);
    ((uint2*)(cn + (size_t)e*D_))[tid] = make_uint2(lo, hi);
}

// ---------------- K2: barrier-free fused prep + sim GEMM + softmax -------------
// grid = NTOK/64 = 512 blocks x 256 thr (4 independent waves). Each WAVE owns
// 16 tokens x all 128 entities; K=1024 streamed in 16 steps of 64.
// NO LDS and NO __syncthreads in the main loop: each lane loads exactly its own
// MFMA A-fragment (fp32 -> f2b in regs, depth-3 prefetch queue, pure SSA);
// B fragments stream from L2-resident cn with 1-step prefetch. K-rotation by
// blockIdx.x de-camps L2 lines. Epilogue is wave-local (LDS, no barrier).
__global__ __launch_bounds__(256) void k_sim(const float* __restrict__ tokens,
                                             const unsigned short* __restrict__ cn,
                                             float* __restrict__ out_assign,
                                             unsigned short* __restrict__ pT,
                                             float* __restrict__ wpart){
    __shared__ __align__(16) char smem[25600];       // 4 waves x 6400B (epilogue only)

    const int tid  = threadIdx.x;
    const int w    = tid >> 6;
    const int lane = tid & 63;
    const int lrow = lane & 15, quad = lane >> 4;

    char* wb = smem + w*6400;
    unsigned short* spT = (unsigned short*)wb;        // [128][24] bf16 (6144 B)
    float* scL = (float*)(wb + 6144);                 // [16]

    const int t0  = blockIdx.x*64 + w*16;             // wave's first global token
    const int bb  = t0 >> 12;
    const int tl0 = t0 & (T_ - 1);

    // A: lane covers row lrow, k-bytes quad*8.. within each 64-float window.
    const float* gA = tokens + (size_t)(t0 + lrow)*D_ + quad*8;
    // B: 8 fragment base pointers.
    const unsigned short* bqp[8];
    #pragma unroll
    for (int ni = 0; ni < 8; ni++)
        bqp[ni] = cn + (size_t)(ni*16 + lrow)*D_ + quad*8;

    const int rot = blockIdx.x & 15;

    f32x4 acc[8];
    #pragma unroll
    for (int ni = 0; ni < 8; ni++) acc[ni] = (f32x4){0.f,0.f,0.f,0.f};

    float ss = 0.f;
    float4 Ar[3][4];          // depth-3 A queue: Ar[0]=A(s), Ar[1]=A(s+1), Ar[2]=A(s+2)
    bf16x8 Bq[8];             // B(s, kk0), prefetched one step ahead

    // prologue
    {
        const int k0 = ((0 + rot) & 15) * 64;
        const int k1 = ((1 + rot) & 15) * 64;
        const int k2 = ((2 + rot) & 15) * 64;
        #pragma unroll
        for (int j = 0; j < 2; j++){
            Ar[0][j]   = *(const float4*)(gA + k0 + j*4);
            Ar[0][2+j] = *(const float4*)(gA + k0 + 32 + j*4);
            Ar[1][j]   = *(const float4*)(gA + k1 + j*4);
            Ar[1][2+j] = *(const float4*)(gA + k1 + 32 + j*4);
            Ar[2][j]   = *(const float4*)(gA + k2 + j*4);
            Ar[2][2+j] = *(const float4*)(gA + k2 + 32 + j*4);
        }
        #pragma unroll
        for (int ni = 0; ni < 8; ni++)
            Bq[ni] = *(const bf16x8*)(bqp[ni] + k0);
    }

    #pragma unroll
    for (int s = 0; s < 16; s++){
        const int kgl  = ((s + rot) & 15) * 64;
        const int kgl1 = ((s + 1 + rot) & 15) * 64;
        const int kgl3 = ((s + 3 + rot) & 15) * 64;

        // 1. B(s, kk1) — issued at top, consumed after the kk0 MFMA cluster
        bf16x8 Bn[8];
        #pragma unroll
        for (int ni = 0; ni < 8; ni++)
            Bn[ni] = *(const bf16x8*)(bqp[ni] + kgl + 32);

        // 2. A(s+3) raw loads (deep prefetch)
        float4 An[4];
        if (s + 3 < 16){
            #pragma unroll
            for (int j = 0; j < 2; j++){
                An[j]   = *(const float4*)(gA + kgl3 + j*4);
                An[2+j] = *(const float4*)(gA + kgl3 + 32 + j*4);
            }
        }

        // 3. B(s+1, kk0) prefetch
        bf16x8 B2[8];
        if (s + 1 < 16){
            #pragma unroll
            for (int ni = 0; ni < 8; ni++)
                B2[ni] = *(const bf16x8*)(bqp[ni] + kgl1);
        }

        // 4. consume A(s): norm partial + convert to MFMA fragments
        float4 a0 = Ar[0][0], a1 = Ar[0][1], a2 = Ar[0][2], a3 = Ar[0][3];
        ss += a0.x*a0.x + a0.y*a0.y + a0.z*a0.z + a0.w*a0.w
            + a1.x*a1.x + a1.y*a1.y + a1.z*a1.z + a1.w*a1.w
            + a2.x*a2.x + a2.y*a2.y + a2.z*a2.z + a2.w*a2.w
            + a3.x*a3.x + a3.y*a3.y + a3.z*a3.z + a3.w*a3.w;
        bf16x8 af0 = pk(a0, a1);
        bf16x8 af1 = pk(a2, a3);

        // 5/6. MFMA clusters
        __builtin_amdgcn_s_setprio(1);
        #pragma unroll
        for (int ni = 0; ni < 8; ni++)
            acc[ni] = __builtin_amdgcn_mfma_f32_16x16x32_bf16(af0, Bq[ni], acc[ni], 0, 0, 0);
        #pragma unroll
        for (int ni = 0; ni < 8; ni++)
            acc[ni] = __builtin_amdgcn_mfma_f32_16x16x32_bf16(af1, Bn[ni], acc[ni], 0, 0, 0);
        __builtin_amdgcn_s_setprio(0);

        // 7. shift queues (pure SSA renames after full unroll)
        #pragma unroll
        for (int j = 0; j < 4; j++){ Ar[0][j] = Ar[1][j]; Ar[1][j] = Ar[2][j]; Ar[2][j] = An[j]; }
        #pragma unroll
        for (int ni = 0; ni < 8; ni++) Bq[ni] = B2[ni];
    }

    // ---- wave-local epilogue (no block barrier) ----
    // row norms: lane holds quarter-row sum for row lrow; combine across quads
    ss += __shfl_xor(ss, 16);
    ss += __shfl_xor(ss, 32);
    if (quad == 0) scL[lrow] = 10.0f / fmaxf(sqrtf(ss), 1e-12f);   // 1/(max(||x||,eps)*TEMP)

    float wp[8];
    #pragma unroll
    for (int ni = 0; ni < 8; ni++) wp[ni] = 0.f;

    #pragma unroll
    for (int rr = 0; rr < 4; rr++){
        const int row = quad*4 + rr;
        const float sc = scL[row];
        float m = -1e30f;
        float v[8];
        #pragma unroll
        for (int ni = 0; ni < 8; ni++){
            const int col = ni*16 + lrow;
            v[ni] = acc[ni][rr] * sc;
            if (col < E_) m = fmaxf(m, v[ni]);
        }
        #pragma unroll
        for (int off = 1; off < 16; off <<= 1) m = fmaxf(m, __shfl_xor(m, off));
        float s = 0.f;
        #pragma unroll
        for (int ni = 0; ni < 8; ni++){
            const int col = ni*16 + lrow;
            s += (col < E_) ? __expf(v[ni] - m) : 0.f;
        }
        #pragma unroll
        for (int off = 1; off < 16; off <<= 1) s += __shfl_xor(s, off);
        const float rinv = 1.0f / s;
        #pragma unroll
        for (int ni = 0; ni < 8; ni++){
            const int col = ni*16 + lrow;
            float p = 0.f;
            if (col < E_){
                p = __expf(v[ni] - m) * rinv;
                out_assign[(size_t)(t0 + row)*E_ + col] = p;
                wp[ni] += p;
            }
            spT[col*24 + row] = f2b(p);
        }
    }
    // weight partials: sum this wave's 16 rows per col
    #pragma unroll
    for (int ni = 0; ni < 8; ni++){
        float vv = wp[ni];
        vv += __shfl_xor(vv, 16);
        vv += __shfl_xor(vv, 32);
        if (quad == 0)
            wpart[((size_t)bb*256 + (tl0 >> 4))*EP_ + ni*16 + lrow] = vv;
    }
    // pT store: lane handles e = lane, lane+64 (16 halfs each)
    #pragma unroll
    for (int j = 0; j < 2; j++){
        const int e = lane + 64*j;
        uint4 v0 = *(const uint4*)(spT + e*24);
        uint4 v1 = *(const uint4*)(spT + e*24 + 8);
        *(uint4*)(pT + ((size_t)bb*EP_ + e)*T_ + tl0)     = v0;
        *(uint4*)(pT + ((size_t)bb*EP_ + e)*T_ + tl0 + 8) = v1;
    }
}

// ---------------- K3: partial entity_features --------------------------------
// grid = (16 d-tiles, TC_ t-chunks, 8 batches) = 1024 blocks. Tile 128e x 64d.
// This round: (a) K-rotation by blockIdx.x (the 16 d-tile blocks share (bb,tc)
// and otherwise camp the same pT/tokens lines); (b) B-raw loads issued BEFORE
// the DMA so the pack never waits on the younger DMA in the vmcnt FIFO.
__global__ __launch_bounds__(256) void k_feat(const float* __restrict__ tokens,
                                              const unsigned short* __restrict__ pT,
                                              float* __restrict__ facc_part){
    const int tid = threadIdx.x;
    const int d0  = blockIdx.x * 64;
    const int tc  = blockIdx.y;
    const int bb  = blockIdx.z;

    __shared__ __align__(16) unsigned short lds_a[2][128*64];   // 2 x 16KB  [e][t]
    __shared__ __align__(16) unsigned short lds_b[2][64*64];    // 2 x 8KB   [d][t]

    const int lane = tid & 63, w = tid >> 6;
    const int wm = w >> 1, wn = w & 1, lrow = lane & 15, quad = lane >> 4;
    const int rot = blockIdx.x & 7;

    // A DMA: wave w fills chunks c=4w..4w+3 (rows 8c..8c+7), swizzled source.
    const unsigned short* gA[4];
    int lAoff[4];
    #pragma unroll
    for (int j = 0; j < 4; j++){
        int c = 4*w + j;
        int brow = 8*c + (lane >> 3);
        int bjg  = (lane & 7) ^ (brow & 7);
        gA[j] = pT + ((size_t)bb*EP_ + brow)*T_ + tc*KT_ + bjg*8;
        lAoff[j] = c*512;
    }

    // B: thread owns d-column dcol (0..63) and t-octets o1, o1+4.
    const int dcol = tid & 63;
    const int o1 = tid >> 6;            // 0..3
    const float* gB = tokens + ((size_t)bb*T_ + (size_t)tc*KT_)*D_ + d0 + dcol;
    const int s1 = o1 ^ (dcol & 7), s2 = (o1 + 4) ^ (dcol & 7);
    const int b1off = dcol*64 + s1*8;
    const int b2off = dcol*64 + s2*8;

    f32x4 acc[4][2];
    #pragma unroll
    for (int i = 0; i < 4; i++)
        #pragma unroll
        for (int j = 0; j < 2; j++) acc[i][j] = (f32x4){0.f,0.f,0.f,0.f};

    // prologue: logical chunk 0 (rotated)
    float b1[8], b2[8];
    {
        const int kg0 = (rot & 7) * 64;
        #pragma unroll
        for (int tt = 0; tt < 8; tt++) b1[tt] = gB[(size_t)(kg0 + o1*8 + tt)*D_];
        #pragma unroll
        for (int tt = 0; tt < 8; tt++) b2[tt] = gB[(size_t)(kg0 + (o1+4)*8 + tt)*D_];
        #pragma unroll
        for (int j = 0; j < 4; j++) dma16(gA[j] + kg0, &lds_a[0][lAoff[j]]);
    }
    *(uint4*)(&lds_b[0][b1off]) = pack8(make_float4(b1[0],b1[1],b1[2],b1[3]),
                                        make_float4(b1[4],b1[5],b1[6],b1[7]));
    *(uint4*)(&lds_b[0][b2off]) = pack8(make_float4(b2[0],b2[1],b2[2],b2[3]),
                                        make_float4(b2[4],b2[5],b2[6],b2[7]));

    for (int ki = 0; ki < 8; ki++){
        const int cur = ki & 1;
        __syncthreads();                       // buffers[cur] ready (vmcnt+lgkm+bar)
        if (ki < 7){
            const int kgn = ((ki + 1 + rot) & 7) * 64;
            #pragma unroll
            for (int tt = 0; tt < 8; tt++) b1[tt] = gB[(size_t)(kgn + o1*8 + tt)*D_];
            #pragma unroll
            for (int tt = 0; tt < 8; tt++) b2[tt] = gB[(size_t)(kgn + (o1+4)*8 + tt)*D_];
            #pragma unroll
            for (int j = 0; j < 4; j++) dma16(gA[j] + kgn, &lds_a[1-cur][lAoff[j]]);
        }
        const unsigned short* aC = &lds_a[cur][0];
        const unsigned short* bC = &lds_b[cur][0];
        #pragma unroll
        for (int kk = 0; kk < 2; kk++){
            const int b = quad + 4*kk;
            bf16x8 af[4], bfr[2];
            #pragma unroll
            for (int mi = 0; mi < 4; mi++){
                const int e = wm*64 + mi*16 + lrow;
                af[mi] = *(const bf16x8*)(aC + e*64 + ((b ^ (e & 7)) * 8));
            }
            #pragma unroll
            for (int ni = 0; ni < 2; ni++){
                const int d = wn*32 + ni*16 + lrow;
                bfr[ni] = *(const bf16x8*)(bC + d*64 + ((b ^ (d & 7)) * 8));
            }
            #pragma unroll
            for (int mi = 0; mi < 4; mi++)
                #pragma unroll
                for (int ni = 0; ni < 2; ni++)
                    acc[mi][ni] = __builtin_amdgcn_mfma_f32_16x16x32_bf16(af[mi], bfr[ni], acc[mi][ni], 0, 0, 0);
        }
        if (ki < 7){
            *(uint4*)(&lds_b[1-cur][b1off]) = pack8(make_float4(b1[0],b1[1],b1[2],b1[3]),
                                                    make_float4(b1[4],b1[5],b1[6],b1[7]));
            *(uint4*)(&lds_b[1-cur][b2off]) = pack8(make_float4(b2[0],b2[1],b2[2],b2[3]),
                                                    make_float4(b2[4],b2[5],b2[6],b2[7]));
        }
    }

    #pragma unroll
    for (int mi = 0; mi < 4; mi++){
        #pragma unroll
        for (int ni = 0; ni < 2; ni++){
            int d = d0 + wn*32 + ni*16 + lrow;
            #pragma unroll
            for (int rr = 0; rr < 4; rr++){
                int e = wm*64 + mi*16 + quad*4 + rr;
                if (e < E_)
                    facc_part[((size_t)(tc*B_ + bb)*E_ + e)*D_ + d] = acc[mi][ni][rr];
            }
        }
    }
}

// ---------------- K4: w = sum chunks; out = (sum parts)/(w+eps) ----------------
// grid = (E_, B_), 256 threads. wpart now has 256 chunks of 16 tokens.
__global__ __launch_bounds__(256) void k_final(const float* __restrict__ wpart,
                                               const float* __restrict__ facc_part,
                                               float* __restrict__ out_feat){
    const int e  = blockIdx.x;
    const int bb = blockIdx.y;
    const int tid = threadIdx.x;

    __shared__ float red[256];
    red[tid] = wpart[((size_t)bb*256 + tid)*EP_ + e];
    __syncthreads();
    for (int st = 128; st > 0; st >>= 1){ if (tid < st) red[tid] += red[tid+st]; __syncthreads(); }
    const float winv = 1.0f / (red[0] + 1e-6f);

    const int d = tid * 4;
    float4 o = make_float4(0.f, 0.f, 0.f, 0.f);
    #pragma unroll
    for (int tc = 0; tc < TC_; tc++){
        float4 p = *(const float4*)(facc_part + ((size_t)(tc*B_ + bb)*E_ + e)*D_ + d);
        o.x += p.x; o.y += p.y; o.z += p.z; o.w += p.w;
    }
    o.x *= winv; o.y *= winv; o.z *= winv; o.w *= winv;
    *(float4*)(out_feat + ((size_t)bb*E_ + e)*D_ + d) = o;
}

extern "C" void kernel_launch(void* const* d_in, const int* in_sizes, int n_in,
                              void* d_out, int out_size, void* d_ws, size_t ws_size,
                              hipStream_t stream){
    const float* tokens = (const float*)d_in[0];
    const float* cent   = (const float*)d_in[1];
    float* out        = (float*)d_out;
    float* out_assign = out;
    float* out_feat   = out + (size_t)B_*T_*E_;

    float* wpart = (float*)d_ws;                                      // B*256*128 f32
    float* facc_part = wpart + (size_t)B_*256*EP_;                    // TC_*B*E*D f32
    unsigned short* cn = (unsigned short*)(facc_part + (size_t)TC_*B_*E_*D_);  // EP_*D_ bf16
    unsigned short* pT = cn + (size_t)EP_*D_;                         // B_*EP_*T_ bf16

    k_cnorm<<<EP_, 256, 0, stream>>>(cent, cn);
    k_sim  <<<NTOK/64, 256, 0, stream>>>(tokens, cn, out_assign, pT, wpart);
    k_feat <<<dim3(16, TC_, B_), 256, 0, stream>>>(tokens, pT, facc_part);
    k_final<<<dim3(E_, B_), 256, 0, stream>>>(wpart, facc_part, out_feat);
}